// Round 9
// baseline (68.147 us; speedup 1.0000x reference)
//
#include <hip/hip_runtime.h>

typedef float v2f __attribute__((ext_vector_type(2)));

#define KDIM 64
#define WAVES_PER_BLOCK 4

#define LOG2E 1.44269504088896f

// one pair-eval for both rows, packed: term = |dg*dd| * log2(1 + 2^(qc*(s-sj)))
__device__ __forceinline__ v2f pair_term(v2f g2, v2f d2, v2f s2,
                                         v2f gj, v2f dj, v2f sj, float qc) {
    v2f pd = (g2 - gj) * (d2 - dj);
    v2f del; del.x = fabsf(pd.x); del.y = fabsf(pd.y);
    v2f u = qc * (s2 - sj);
    v2f e; e.x = __builtin_amdgcn_exp2f(u.x); e.y = __builtin_amdgcn_exp2f(u.y);
    v2f le = 1.0f + e;
    v2f l; l.x = __builtin_amdgcn_logf(le.x); l.y = __builtin_amdgcn_logf(le.y);
    return del * l;
}

// quad_perm DPP: rotate within each 4-lane quad (pure VALU, no DS traffic)
template <int CTRL>
__device__ __forceinline__ float dpp_qperm(float x) {
    return __uint_as_float((unsigned int)__builtin_amdgcn_update_dpp(
        0, (int)__float_as_uint(x), CTRL, 0xF, 0xF, true));
}
#define QROT1 0x93  // lane i <- i-1 in quad
#define QROT2 0x4E  // lane i <- i-2 in quad

// one inter-quad chunk: lane i vs the 4 lanes of quad (qi - t) & 15
__device__ __forceinline__ v2f chunk(const v2f* sbuf, const v2f* gbuf,
                                     const v2f* dbuf, int qi, int t,
                                     v2f s2, v2f g2, v2f d2) {
    const int Q = (qi + 16 - t) << 2;  // item index in doubled buffer
    float4 sa = *(const float4*)&sbuf[Q], sb = *(const float4*)&sbuf[Q + 2];
    float4 ga = *(const float4*)&gbuf[Q], gb = *(const float4*)&gbuf[Q + 2];
    float4 da = *(const float4*)&dbuf[Q], db = *(const float4*)&dbuf[Q + 2];
    const float qc = (qi >= t) ? LOG2E : -LOG2E;  // sign of (s_i - s_j): j<i <=> qi>=t
    v2f term = pair_term(g2, d2, s2, v2f{ga.x, ga.y}, v2f{da.x, da.y}, v2f{sa.x, sa.y}, qc);
    term = term + pair_term(g2, d2, s2, v2f{ga.z, ga.w}, v2f{da.z, da.w}, v2f{sa.z, sa.w}, qc);
    term = term + pair_term(g2, d2, s2, v2f{gb.x, gb.y}, v2f{db.x, db.y}, v2f{sb.x, sb.y}, qc);
    term = term + pair_term(g2, d2, s2, v2f{gb.z, gb.w}, v2f{db.z, db.w}, v2f{sb.z, sb.w}, qc);
    return term;
}

__global__ __launch_bounds__(256) void rankdpo_main(
    const float* __restrict__ s_in, const float* __restrict__ r_in,
    float* __restrict__ partials, int B)
{
    const int wave = threadIdx.x >> 6;
    const int lane = threadIdx.x & 63;
    const int qi = lane >> 2;
    const int bi = lane & 3;

    // Each row-pair is processed by TWO waves (h=0: chunks t=1..4,
    // h=1: t=5..8 + intra-quad) -> 2x grid, 32 waves/CU, full occupancy.
    const int wave_id = blockIdx.x * WAVES_PER_BLOCK + wave;
    const int rp = wave_id >> 1;
    const int h  = wave_id & 1;
    const int row0 = 2 * rp;
    const int row1 = row0 + 1;
    const int a0 = (row0 < B ? row0 : 0) * KDIM + lane;
    const int a1 = (row1 < B ? row1 : 0) * KDIM + lane;

    const float s0 = s_in[a0], r0 = r_in[a0];
    const float s1 = s_in[a1], r1 = r_in[a1];

    // per-wave-private LDS, row-interleaved, doubled for wrap-free rotation.
    __shared__ __align__(16) v2f shs[WAVES_PER_BLOCK][128];
    __shared__ __align__(16) v2f shg[WAVES_PER_BLOCK][128];
    __shared__ __align__(16) v2f shd[WAVES_PER_BLOCK][128];
    __shared__ __align__(16) v2f shr[WAVES_PER_BLOCK][64];  // rank scan, no rotation
    v2f* sbuf = shs[wave];
    v2f* gbuf = shg[wave];
    v2f* dbuf = shd[wave];
    v2f* rbuf = shr[wave];

    rbuf[lane] = v2f{r0, r1};
    sbuf[lane] = v2f{s0, s1};  sbuf[lane + 64] = v2f{s0, s1};

    // ---- rank: count strictly-greater rewards via broadcast b128 reads ----
    // (DS broadcast reads are near-free; R7 showed readlane variant loads the
    //  binding VALU pipe. Tiebreak-free is exact here: absmax 0.0 since R6.)
    int c0 = 0, c1 = 0;
    #pragma unroll
    for (int t = 0; t < 16; ++t) {
        float4 qa = *(const float4*)&rbuf[4 * t];
        float4 qb = *(const float4*)&rbuf[4 * t + 2];
        c0 += (qa.x > r0) + (qa.z > r0) + (qb.x > r0) + (qb.z > r0);
        c1 += (qa.y > r1) + (qa.w > r1) + (qb.y > r1) + (qb.w > r1);
    }
    // invd' = 1/log2(rank+1) = ln2/ln(rank+1); ln2 pre-folded for raw exp2/log2
    const float invd0 = __builtin_amdgcn_rcpf(__builtin_amdgcn_logf((float)(c0 + 2)));
    const float invd1 = __builtin_amdgcn_rcpf(__builtin_amdgcn_logf((float)(c1 + 2)));
    const float g0 = 2.0f * r0 - 1.0f;
    const float g1 = 2.0f * r1 - 1.0f;

    gbuf[lane] = v2f{g0, g1};        gbuf[lane + 64] = v2f{g0, g1};
    dbuf[lane] = v2f{invd0, invd1};  dbuf[lane + 64] = v2f{invd0, invd1};

    const v2f s2 = {s0, s1}, g2 = {g0, g1}, d2 = {invd0, invd1};
    v2f p = {0.0f, 0.0f};

    if (h == 0) {
        // chunks t=1..4 (each unordered quad-pair exactly once, all lanes useful)
        p = p + chunk(sbuf, gbuf, dbuf, qi, 1, s2, g2, d2);
        p = p + chunk(sbuf, gbuf, dbuf, qi, 2, s2, g2, d2);
        p = p + chunk(sbuf, gbuf, dbuf, qi, 3, s2, g2, d2);
        p = p + chunk(sbuf, gbuf, dbuf, qi, 4, s2, g2, d2);
    } else {
        // chunks t=5..7 full; t=8 doubled -> keep qi>=8; plus intra-quad pairs
        p = p + chunk(sbuf, gbuf, dbuf, qi, 5, s2, g2, d2);
        p = p + chunk(sbuf, gbuf, dbuf, qi, 6, s2, g2, d2);
        p = p + chunk(sbuf, gbuf, dbuf, qi, 7, s2, g2, d2);
        const float keep8 = (qi >= 8) ? 1.0f : 0.0f;
        p = p + chunk(sbuf, gbuf, dbuf, qi, 8, s2, g2, d2) * keep8;

        // intra-quad: d=1 full (sign bi>=1), d=2 keep bi>=2 (else doubled)
        const float qcA = (bi >= 1) ? LOG2E : -LOG2E;
        const float keepB = (bi >= 2) ? 1.0f : 0.0f;
        v2f sjA = {dpp_qperm<QROT1>(s0), dpp_qperm<QROT1>(s1)};
        v2f gjA = {dpp_qperm<QROT1>(g0), dpp_qperm<QROT1>(g1)};
        v2f djA = {dpp_qperm<QROT1>(invd0), dpp_qperm<QROT1>(invd1)};
        v2f sjB = {dpp_qperm<QROT2>(s0), dpp_qperm<QROT2>(s1)};
        v2f gjB = {dpp_qperm<QROT2>(g0), dpp_qperm<QROT2>(g1)};
        v2f djB = {dpp_qperm<QROT2>(invd0), dpp_qperm<QROT2>(invd1)};
        p = p + pair_term(g2, d2, s2, gjA, djA, sjA, qcA);
        p = p + pair_term(g2, d2, s2, gjB, djB, sjB, LOG2E) * keepB;
    }

    if (row0 >= B) p.x = 0.0f;
    if (row1 >= B) p.y = 0.0f;

    float pacc = p.x + p.y;
    #pragma unroll
    for (int off = 32; off > 0; off >>= 1)
        pacc += __shfl_down(pacc, off);

    __shared__ float wsum[WAVES_PER_BLOCK];
    if (lane == 0) wsum[wave] = pacc;
    __syncthreads();
    if (threadIdx.x == 0)
        partials[blockIdx.x] = wsum[0] + wsum[1] + wsum[2] + wsum[3];
}

__global__ __launch_bounds__(256) void rankdpo_reduce(
    const float* __restrict__ partials, int n, float* __restrict__ out,
    double inv_count)
{
    double sum = 0.0;
    for (int i = threadIdx.x; i < n; i += 256)
        sum += (double)partials[i];
    __shared__ double sh[256];
    sh[threadIdx.x] = sum;
    __syncthreads();
    for (int st = 128; st > 0; st >>= 1) {
        if (threadIdx.x < st) sh[threadIdx.x] += sh[threadIdx.x + st];
        __syncthreads();
    }
    if (threadIdx.x == 0)
        out[0] = (float)(sh[0] * inv_count);
}

extern "C" void kernel_launch(void* const* d_in, const int* in_sizes, int n_in,
                              void* d_out, int out_size, void* d_ws, size_t ws_size,
                              hipStream_t stream) {
    const float* s = (const float*)d_in[0];   // policy_logps [B,K] f32
    const float* r = (const float*)d_in[1];   // reward_scores [B,K] f32
    float* out = (float*)d_out;

    const int BK = in_sizes[0];
    const int B  = BK / KDIM;
    const int npairs = (B + 1) / 2;
    const int nwaves = 2 * npairs;                       // two waves per row-pair
    const int nblocks = (nwaves + WAVES_PER_BLOCK - 1) / WAVES_PER_BLOCK;

    float* partials = (float*)d_ws;  // nblocks floats, all written before read

    const long long count = (long long)B * (KDIM * (KDIM - 1) / 2);
    const double inv_count = 1.0 / (double)count;

    rankdpo_main<<<nblocks, 256, 0, stream>>>(s, r, partials, B);
    rankdpo_reduce<<<1, 256, 0, stream>>>(partials, nblocks, out, inv_count);
}

// Round 10
// 66.104 us; speedup vs baseline: 1.0309x; 1.0309x over previous
//
#include <hip/hip_runtime.h>

typedef float v2f __attribute__((ext_vector_type(2)));

#define KDIM 64
#define WAVES_PER_BLOCK 4
#define ROWS_PER_WAVE 4
#define ROWS_PER_BLOCK (WAVES_PER_BLOCK * ROWS_PER_WAVE)  // 16

#define LOG2E 1.44269504088896f

// one pair-eval for two rows, packed. delta uses |Δr| (= |Δg|/2; the 2 is
// folded into inv_count on the host). term = |Δr·Δd| * log2(1 + 2^(qc·Δs))
__device__ __forceinline__ v2f pair_term(v2f r2, v2f d2, v2f s2,
                                         v2f rj, v2f dj, v2f sj, float qc) {
    v2f pd = (r2 - rj) * (d2 - dj);
    v2f del; del.x = fabsf(pd.x); del.y = fabsf(pd.y);
    v2f u = qc * (s2 - sj);
    v2f e; e.x = __builtin_amdgcn_exp2f(u.x); e.y = __builtin_amdgcn_exp2f(u.y);
    v2f le = 1.0f + e;
    v2f l; l.x = __builtin_amdgcn_logf(le.x); l.y = __builtin_amdgcn_logf(le.y);
    return del * l;
}

// quad_perm DPP: rotate within each 4-lane quad (pure VALU, no DS traffic)
template <int CTRL>
__device__ __forceinline__ float dpp_qperm(float x) {
    return __uint_as_float((unsigned int)__builtin_amdgcn_update_dpp(
        0, (int)__float_as_uint(x), CTRL, 0xF, 0xF, true));
}
#define QROT1 0x93  // lane i <- i-1 in quad
#define QROT2 0x4E  // lane i <- i-2 in quad

// one inter-quad chunk: lane i vs the 4 lanes of quad (qi - t) & 15
__device__ __forceinline__ v2f chunk(const v2f* sbuf, const v2f* rbuf,
                                     const v2f* dbuf, int qi, int t,
                                     v2f s2, v2f r2, v2f d2) {
    const int Q = (qi + 16 - t) << 2;  // item index in doubled buffer
    float4 sa = *(const float4*)&sbuf[Q], sb = *(const float4*)&sbuf[Q + 2];
    float4 ra = *(const float4*)&rbuf[Q], rb = *(const float4*)&rbuf[Q + 2];
    float4 da = *(const float4*)&dbuf[Q], db = *(const float4*)&dbuf[Q + 2];
    const float qc = (qi >= t) ? LOG2E : -LOG2E;  // sign of Δs: j<i <=> qi>=t
    v2f term = pair_term(r2, d2, s2, v2f{ra.x, ra.y}, v2f{da.x, da.y}, v2f{sa.x, sa.y}, qc);
    term = term + pair_term(r2, d2, s2, v2f{ra.z, ra.w}, v2f{da.z, da.w}, v2f{sa.z, sa.w}, qc);
    term = term + pair_term(r2, d2, s2, v2f{rb.x, rb.y}, v2f{db.x, db.y}, v2f{sb.x, sb.y}, qc);
    term = term + pair_term(r2, d2, s2, v2f{rb.z, rb.w}, v2f{db.z, db.w}, v2f{sb.z, sb.w}, qc);
    return term;
}

__global__ __launch_bounds__(256) void rankdpo_main(
    const float* __restrict__ s_in, const float* __restrict__ r_in,
    float* __restrict__ partials, int B)
{
    const int wave = threadIdx.x >> 6;
    const int lane = threadIdx.x & 63;
    const int qi = lane >> 2;
    const int bi = lane & 3;

    // 4 rows per wave = two independent packed pipelines (A: rows 0,1;
    // B: rows 2,3). ILP across pipelines hides DS/trans latency; per-wave
    // fixed costs amortize over 2x rows (R9 showed extra TLP at extra work
    // regresses; this is the opposite trade).
    const int base = (blockIdx.x * WAVES_PER_BLOCK + wave) * ROWS_PER_WAVE;
    const int row0 = base, row1 = base + 1, row2 = base + 2, row3 = base + 3;
    const int a0 = (row0 < B ? row0 : 0) * KDIM + lane;
    const int a1 = (row1 < B ? row1 : 0) * KDIM + lane;
    const int a2 = (row2 < B ? row2 : 0) * KDIM + lane;
    const int a3 = (row3 < B ? row3 : 0) * KDIM + lane;

    const float s0 = s_in[a0], r0 = r_in[a0];
    const float s1 = s_in[a1], r1 = r_in[a1];
    const float s2s = s_in[a2], r2s = r_in[a2];
    const float s3 = s_in[a3], r3 = r_in[a3];

    // per-wave-private LDS, row-interleaved, doubled for wrap-free rotation.
    // arrays per wave: [0]=sA [1]=rA [2]=dA [3]=sB [4]=rB [5]=dB
    __shared__ __align__(16) v2f sh[WAVES_PER_BLOCK][6][128];
    v2f* sA = sh[wave][0]; v2f* rA = sh[wave][1]; v2f* dA = sh[wave][2];
    v2f* sB = sh[wave][3]; v2f* rB = sh[wave][4]; v2f* dB = sh[wave][5];

    sA[lane] = v2f{s0, s1};   sA[lane + 64] = v2f{s0, s1};
    rA[lane] = v2f{r0, r1};   rA[lane + 64] = v2f{r0, r1};
    sB[lane] = v2f{s2s, s3};  sB[lane + 64] = v2f{s2s, s3};
    rB[lane] = v2f{r2s, r3};  rB[lane + 64] = v2f{r2s, r3};

    // ---- rank: count strictly-greater rewards via broadcast b128 reads ----
    // (DS broadcast is cheap and off the VALU pipe — R7's readlane variant
    //  regressed. Tiebreak-free is exact here: absmax 0.0 since R6.)
    int c0 = 0, c1 = 0, c2 = 0, c3 = 0;
    #pragma unroll
    for (int t = 0; t < 16; ++t) {
        float4 qa = *(const float4*)&rA[4 * t];
        float4 qb = *(const float4*)&rA[4 * t + 2];
        float4 qc4 = *(const float4*)&rB[4 * t];
        float4 qd = *(const float4*)&rB[4 * t + 2];
        c0 += (qa.x > r0) + (qa.z > r0) + (qb.x > r0) + (qb.z > r0);
        c1 += (qa.y > r1) + (qa.w > r1) + (qb.y > r1) + (qb.w > r1);
        c2 += (qc4.x > r2s) + (qc4.z > r2s) + (qd.x > r2s) + (qd.z > r2s);
        c3 += (qc4.y > r3) + (qc4.w > r3) + (qd.y > r3) + (qd.w > r3);
    }
    // invd' = 1/log2(rank+1) = ln2/ln(rank+1); ln2 pre-folded for raw exp2/log2
    const float invd0 = __builtin_amdgcn_rcpf(__builtin_amdgcn_logf((float)(c0 + 2)));
    const float invd1 = __builtin_amdgcn_rcpf(__builtin_amdgcn_logf((float)(c1 + 2)));
    const float invd2 = __builtin_amdgcn_rcpf(__builtin_amdgcn_logf((float)(c2 + 2)));
    const float invd3 = __builtin_amdgcn_rcpf(__builtin_amdgcn_logf((float)(c3 + 2)));

    dA[lane] = v2f{invd0, invd1};  dA[lane + 64] = v2f{invd0, invd1};
    dB[lane] = v2f{invd2, invd3};  dB[lane + 64] = v2f{invd2, invd3};

    const v2f sa2 = {s0, s1},  ra2 = {r0, r1},  da2 = {invd0, invd1};
    const v2f sb2 = {s2s, s3}, rb2 = {r2s, r3}, db2 = {invd2, invd3};
    v2f pA = {0.0f, 0.0f}, pB = {0.0f, 0.0f};

    // ---- inter-quad covering: lane i vs the 4 lanes of quad (qi - t) & 15 ----
    // t=1..7: each unordered pair exactly once, all lanes useful.
    // t=8: pairs doubled -> keep qi>=8.
    const float keep8 = (qi >= 8) ? 1.0f : 0.0f;
    #pragma unroll
    for (int t = 1; t <= 7; ++t) {
        pA = pA + chunk(sA, rA, dA, qi, t, sa2, ra2, da2);
        pB = pB + chunk(sB, rB, dB, qi, t, sb2, rb2, db2);
    }
    pA = pA + chunk(sA, rA, dA, qi, 8, sa2, ra2, da2) * keep8;
    pB = pB + chunk(sB, rB, dB, qi, 8, sb2, rb2, db2) * keep8;

    // ---- intra-quad pairs via DPP quad_perm (zero DS traffic) ----
    // d=1: full, sign bi>=1.  d=2: keep bi>=2 (else doubled), j<i.
    {
        const float qcA = (bi >= 1) ? LOG2E : -LOG2E;
        const float keepB = (bi >= 2) ? 1.0f : 0.0f;

        v2f sj1A = {dpp_qperm<QROT1>(s0), dpp_qperm<QROT1>(s1)};
        v2f rj1A = {dpp_qperm<QROT1>(r0), dpp_qperm<QROT1>(r1)};
        v2f dj1A = {dpp_qperm<QROT1>(invd0), dpp_qperm<QROT1>(invd1)};
        v2f sj1B = {dpp_qperm<QROT1>(s2s), dpp_qperm<QROT1>(s3)};
        v2f rj1B = {dpp_qperm<QROT1>(r2s), dpp_qperm<QROT1>(r3)};
        v2f dj1B = {dpp_qperm<QROT1>(invd2), dpp_qperm<QROT1>(invd3)};
        pA = pA + pair_term(ra2, da2, sa2, rj1A, dj1A, sj1A, qcA);
        pB = pB + pair_term(rb2, db2, sb2, rj1B, dj1B, sj1B, qcA);

        v2f sj2A = {dpp_qperm<QROT2>(s0), dpp_qperm<QROT2>(s1)};
        v2f rj2A = {dpp_qperm<QROT2>(r0), dpp_qperm<QROT2>(r1)};
        v2f dj2A = {dpp_qperm<QROT2>(invd0), dpp_qperm<QROT2>(invd1)};
        v2f sj2B = {dpp_qperm<QROT2>(s2s), dpp_qperm<QROT2>(s3)};
        v2f rj2B = {dpp_qperm<QROT2>(r2s), dpp_qperm<QROT2>(r3)};
        v2f dj2B = {dpp_qperm<QROT2>(invd2), dpp_qperm<QROT2>(invd3)};
        pA = pA + pair_term(ra2, da2, sa2, rj2A, dj2A, sj2A, LOG2E) * keepB;
        pB = pB + pair_term(rb2, db2, sb2, rj2B, dj2B, sj2B, LOG2E) * keepB;
    }

    if (row0 >= B) pA.x = 0.0f;
    if (row1 >= B) pA.y = 0.0f;
    if (row2 >= B) pB.x = 0.0f;
    if (row3 >= B) pB.y = 0.0f;

    float pacc = (pA.x + pA.y) + (pB.x + pB.y);
    #pragma unroll
    for (int off = 32; off > 0; off >>= 1)
        pacc += __shfl_down(pacc, off);

    __shared__ float wsum[WAVES_PER_BLOCK];
    if (lane == 0) wsum[wave] = pacc;
    __syncthreads();
    if (threadIdx.x == 0)
        partials[blockIdx.x] = wsum[0] + wsum[1] + wsum[2] + wsum[3];
}

__global__ __launch_bounds__(256) void rankdpo_reduce(
    const float* __restrict__ partials, int n, float* __restrict__ out,
    double inv_count)
{
    double sum = 0.0;
    for (int i = threadIdx.x; i < n; i += 256)
        sum += (double)partials[i];
    __shared__ double sh[256];
    sh[threadIdx.x] = sum;
    __syncthreads();
    for (int st = 128; st > 0; st >>= 1) {
        if (threadIdx.x < st) sh[threadIdx.x] += sh[threadIdx.x + st];
        __syncthreads();
    }
    if (threadIdx.x == 0)
        out[0] = (float)(sh[0] * inv_count);
}

extern "C" void kernel_launch(void* const* d_in, const int* in_sizes, int n_in,
                              void* d_out, int out_size, void* d_ws, size_t ws_size,
                              hipStream_t stream) {
    const float* s = (const float*)d_in[0];   // policy_logps [B,K] f32
    const float* r = (const float*)d_in[1];   // reward_scores [B,K] f32
    float* out = (float*)d_out;

    const int BK = in_sizes[0];
    const int B  = BK / KDIM;
    const int nblocks = (B + ROWS_PER_BLOCK - 1) / ROWS_PER_BLOCK;

    float* partials = (float*)d_ws;  // nblocks floats, all written before read

    const long long count = (long long)B * (KDIM * (KDIM - 1) / 2);
    // factor 2 folds |Δg| = 2|Δr| (g dropped from the kernel entirely)
    const double inv_count = 2.0 / (double)count;

    rankdpo_main<<<nblocks, 256, 0, stream>>>(s, r, partials, B);
    rankdpo_reduce<<<1, 256, 0, stream>>>(partials, nblocks, out, inv_count);
}